// Round 1
// baseline (86.153 us; speedup 1.0000x reference)
//
#include <hip/hip_runtime.h>

#define HW 16384      // 128*128
#define BS 8
#define NC 256        // feature channels
#define K  19         // classes
#define Q  2975
#define INV_T 5.0f    // 1/0.2

// ---------------- K0: zero the accumulators + loss cell ----------------
__global__ void k0_zero(float* __restrict__ sums, int* __restrict__ counts,
                        float* __restrict__ loss) {
    int t = threadIdx.x;
    for (int i = t; i < K * NC; i += 256) sums[i] = 0.f;
    if (t < K) counts[t] = 0;
    if (t == 0) *loss = 0.f;
}

// ---------------- K1: argmax over classes + copy res -> out + histogram ----------------
// one thread per pixel (b,p); reads res[b,k,p] coalesced across threads for each k
__global__ void k1_argmax(const float* __restrict__ res, float* __restrict__ out,
                          unsigned char* __restrict__ pred, int* __restrict__ counts) {
    __shared__ int hist[K];
    int t = threadIdx.x;
    if (t < K) hist[t] = 0;
    __syncthreads();
    int gp = blockIdx.x * 256 + t;          // 0 .. BS*HW-1
    int b  = gp >> 14;                      // / HW
    int p  = gp & (HW - 1);
    const float* rbase = res + (size_t)(b * K) * HW + p;
    float best = rbase[0];
    int   bk   = 0;
    out[(size_t)(b * K) * HW + p] = best;
    #pragma unroll
    for (int k = 1; k < K; ++k) {
        float v = rbase[(size_t)k * HW];
        out[(size_t)(b * K + k) * HW + p] = v;
        if (v > best) { best = v; bk = k; }   // strict > keeps first index (argmax tie rule)
    }
    pred[gp] = (unsigned char)bk;
    atomicAdd(&hist[bk], 1);
    __syncthreads();
    if (t < K) atomicAdd(&counts[t], hist[t]);
}

// ---------------- K2: per-class pooling: sums[k][c] = sum of fea over pred==k ----------------
// one block per (b,c) row; each thread owns LDS column acc[k][tid] -> no atomics,
// bank = tid%32 -> conflict-free
__global__ void __launch_bounds__(256) k2_pool(const float* __restrict__ fea,
                                               const unsigned char* __restrict__ pred,
                                               float* __restrict__ sums) {
    __shared__ float acc[K * 256];
    int t = threadIdx.x;
    int b = blockIdx.x >> 8;
    int c = blockIdx.x & 255;
    #pragma unroll
    for (int k = 0; k < K; ++k) acc[k * 256 + t] = 0.f;
    __syncthreads();
    const float4* f4 = (const float4*)(fea + (size_t)(b * NC + c) * HW);
    const uchar4* p4 = (const uchar4*)(pred + (size_t)b * HW);
    for (int i = t; i < HW / 4; i += 256) {
        float4 v  = f4[i];
        uchar4 kk = p4[i];
        acc[kk.x * 256 + t] += v.x;
        acc[kk.y * 256 + t] += v.y;
        acc[kk.z * 256 + t] += v.z;
        acc[kk.w * 256 + t] += v.w;
    }
    __syncthreads();
    // tree-reduce the 256 columns for each k
    for (int s = 128; s > 0; s >>= 1) {
        for (int idx = t; idx < K * s; idx += 256) {
            int k = idx / s, j = idx - k * s;
            acc[k * 256 + j] += acc[k * 256 + j + s];
        }
        __syncthreads();
    }
    if (t < K) atomicAdd(&sums[t * 256 + c], acc[t * 256]);
}

// ---------------- K3: keys = normalize(sums / max(counts,1)) along c ----------------
__global__ void k3_keys(const float* __restrict__ sums, const int* __restrict__ counts,
                        float* __restrict__ keys) {
    __shared__ float red[256];
    int t = threadIdx.x;
    for (int k = 0; k < K; ++k) {
        float denom = fmaxf((float)counts[k], 1.0f);
        float v = sums[k * 256 + t] / denom;
        red[t] = v * v;
        __syncthreads();
        for (int s = 128; s > 0; s >>= 1) {
            if (t < s) red[t] += red[t + s];
            __syncthreads();
        }
        float nrm = fmaxf(sqrtf(red[0]), 1e-12f);
        __syncthreads();            // everyone read red[0] before next iter overwrites
        keys[k * 256 + t] = v / nrm;
    }
}

// ---------------- K4: loss = sum_k present * mean_c (lse - logit0) ----------------
// one block per c; thread t handles q = t, t+256, ...; online logsumexp per k in registers
__global__ void __launch_bounds__(256) k4_loss(const float* __restrict__ queues,
                                               const float* __restrict__ keys,
                                               const int* __restrict__ counts,
                                               float* __restrict__ loss) {
    int t = threadIdx.x;
    int c = blockIdx.x;
    int lane = t & 63, wv = t >> 6;
    float key[K], m[K], s[K];
    #pragma unroll
    for (int k = 0; k < K; ++k) {
        key[k] = keys[k * 256 + c] * INV_T;
        m[k] = -1e30f;
        s[k] = 0.f;
    }
    for (int q = t; q < Q; q += 256) {
        float qv[K];
        float qs = 0.f;
        #pragma unroll
        for (int k = 0; k < K; ++k) {
            qv[k] = queues[(size_t)(k * 256 + c) * Q + q];
            qs += qv[k];
        }
        #pragma unroll
        for (int k = 0; k < K; ++k) {
            float a  = key[k] * qv[k];            // l_pos/T
            float bn = key[k] * (qs - qv[k]);     // l_neg/T
            float mx = fmaxf(a, bn);
            float mn = fmaxf(m[k], mx);
            s[k] = s[k] * __expf(m[k] - mn) + __expf(a - mn) + __expf(bn - mn);
            m[k] = mn;
        }
    }
    // per-wave shuffle combine of (m,s), then cross-wave via LDS
    __shared__ float mw[K][4], sw[K][4];
    #pragma unroll
    for (int k = 0; k < K; ++k) {
        float mk = m[k], sk = s[k];
        #pragma unroll
        for (int off = 32; off > 0; off >>= 1) {
            float om = __shfl_xor(mk, off, 64);
            float os = __shfl_xor(sk, off, 64);
            float M  = fmaxf(mk, om);
            sk = sk * __expf(mk - M) + os * __expf(om - M);
            mk = M;
        }
        if (lane == 0) { mw[k][wv] = mk; sw[k][wv] = sk; }
    }
    __syncthreads();
    __shared__ float contrib[K];
    if (t < K) {
        float M = mw[t][0], S = sw[t][0];
        for (int w = 1; w < 4; ++w) {
            float M2 = fmaxf(M, mw[t][w]);
            S = S * __expf(M - M2) + sw[t][w] * __expf(mw[t][w] - M2);
            M = M2;
        }
        float lse  = M + logf(S);
        float pos0 = key[t] * queues[(size_t)(t * 256 + c) * Q];  // key already has 1/T
        contrib[t] = (counts[t] > 0) ? (lse - pos0) : 0.f;
    }
    __syncthreads();
    if (t == 0) {
        float sum = 0.f;
        for (int k = 0; k < K; ++k) sum += contrib[k];
        atomicAdd(loss, sum * (1.0f / 256.0f));
    }
}

extern "C" void kernel_launch(void* const* d_in, const int* in_sizes, int n_in,
                              void* d_out, int out_size, void* d_ws, size_t ws_size,
                              hipStream_t stream) {
    const float* fea    = (const float*)d_in[0];   // [8,256,128,128]
    const float* res    = (const float*)d_in[1];   // [8,19,128,128]
    const float* queues = (const float*)d_in[2];   // [19,256,2975]

    float* out  = (float*)d_out;                       // res copy, then loss scalar
    float* loss = out + (size_t)BS * K * HW;           // element 2490368

    char* ws = (char*)d_ws;
    float*         sums   = (float*)(ws);              // 19*256 f32   (19456 B)
    float*         keys   = (float*)(ws + 19456);      // 19*256 f32   (19456 B)
    int*           counts = (int*)(ws + 38912);        // 19 ints
    unsigned char* pred   = (unsigned char*)(ws + 39040); // 131072 B

    hipLaunchKernelGGL(k0_zero,   dim3(1),    dim3(256), 0, stream, sums, counts, loss);
    hipLaunchKernelGGL(k1_argmax, dim3(BS * HW / 256), dim3(256), 0, stream, res, out, pred, counts);
    hipLaunchKernelGGL(k2_pool,   dim3(BS * NC), dim3(256), 0, stream, fea, pred, sums);
    hipLaunchKernelGGL(k3_keys,   dim3(1),    dim3(256), 0, stream, sums, counts, keys);
    hipLaunchKernelGGL(k4_loss,   dim3(NC),   dim3(256), 0, stream, queues, keys, counts, loss);
}

// Round 2
// 77.004 us; speedup vs baseline: 1.1188x; 1.1188x over previous
//
#include <hip/hip_runtime.h>

#define HW 16384      // 128*128
#define BS 8
#define NC 256        // feature channels
#define K  19         // classes
#define Q  2975
#define INV_T 5.0f    // 1/0.2
#define NCHUNK 4
#define QC 744        // ceil(Q/NCHUNK)

// ---------------- K0: zero sums + counts ----------------
__global__ void k0_zero(float* __restrict__ sums, int* __restrict__ counts) {
    int t = threadIdx.x;
    for (int i = t; i < K * NC; i += 256) sums[i] = 0.f;
    if (t < K) counts[t] = 0;
}

// ---------------- K1: argmax over classes + copy res -> out + histogram ----------------
// float2-vectorized: each thread owns 2 consecutive pixels
__global__ void k1_argmax(const float* __restrict__ res, float* __restrict__ out,
                          unsigned char* __restrict__ pred, int* __restrict__ counts) {
    __shared__ int hist[K];
    int t = threadIdx.x;
    if (t < K) hist[t] = 0;
    __syncthreads();
    int gp2 = blockIdx.x * 256 + t;          // float2 group id
    int b   = gp2 >> 13;                     // / (HW/2)
    int p2  = gp2 & (HW / 2 - 1);
    const float2* rbase = (const float2*)(res + (size_t)b * K * HW) + p2;
    float2*       obase = (float2*)(out + (size_t)b * K * HW) + p2;
    float2 v = rbase[0];
    obase[0] = v;
    float bx = v.x, by = v.y;
    int   kx = 0,  ky = 0;
    #pragma unroll
    for (int k = 1; k < K; ++k) {
        float2 w = rbase[(size_t)k * (HW / 2)];
        obase[(size_t)k * (HW / 2)] = w;
        if (w.x > bx) { bx = w.x; kx = k; }
        if (w.y > by) { by = w.y; ky = k; }
    }
    uchar2* pp = (uchar2*)pred + ((size_t)b * (HW / 2) + p2);
    uchar2 pk; pk.x = (unsigned char)kx; pk.y = (unsigned char)ky;
    *pp = pk;
    atomicAdd(&hist[kx], 1);
    atomicAdd(&hist[ky], 1);
    __syncthreads();
    if (t < K) atomicAdd(&counts[t], hist[t]);
}

// ---------------- K2: per-class pooling: sums[k][c] = sum of fea over pred==k ----------------
// one block per (b,c) row; each thread owns LDS column acc[k][tid] -> no atomics,
// bank = tid%32 -> conflict-free
__global__ void __launch_bounds__(256) k2_pool(const float* __restrict__ fea,
                                               const unsigned char* __restrict__ pred,
                                               float* __restrict__ sums) {
    __shared__ float acc[K * 256];
    int t = threadIdx.x;
    int b = blockIdx.x >> 8;
    int c = blockIdx.x & 255;
    #pragma unroll
    for (int k = 0; k < K; ++k) acc[k * 256 + t] = 0.f;
    __syncthreads();
    const float4* f4 = (const float4*)(fea + (size_t)(b * NC + c) * HW);
    const uchar4* p4 = (const uchar4*)(pred + (size_t)b * HW);
    for (int i = t; i < HW / 4; i += 256) {
        float4 v  = f4[i];
        uchar4 kk = p4[i];
        acc[kk.x * 256 + t] += v.x;
        acc[kk.y * 256 + t] += v.y;
        acc[kk.z * 256 + t] += v.z;
        acc[kk.w * 256 + t] += v.w;
    }
    __syncthreads();
    for (int s = 128; s > 0; s >>= 1) {
        for (int idx = t; idx < K * s; idx += 256) {
            int k = idx / s, j = idx - k * s;
            acc[k * 256 + j] += acc[k * 256 + j + s];
        }
        __syncthreads();
    }
    if (t < K) atomicAdd(&sums[t * 256 + c], acc[t * 256]);
}

// ---------------- K3: keys = normalize(sums / max(counts,1)) along c ----------------
// wave w handles classes k = w, w+4, ... ; float4 loads, shuffle reduce, no barriers
__global__ void k3_keys(const float* __restrict__ sums, const int* __restrict__ counts,
                        float* __restrict__ keys) {
    int t = threadIdx.x, lane = t & 63, w = t >> 6;
    const float4* s4 = (const float4*)sums;
    float4*       o4 = (float4*)keys;
    for (int k = w; k < K; k += 4) {
        float denom = fmaxf((float)counts[k], 1.0f);
        float4 v = s4[k * 64 + lane];
        v.x /= denom; v.y /= denom; v.z /= denom; v.w /= denom;
        float ss = v.x * v.x + v.y * v.y + v.z * v.z + v.w * v.w;
        #pragma unroll
        for (int off = 32; off > 0; off >>= 1) ss += __shfl_xor(ss, off, 64);
        float inv = 1.0f / fmaxf(sqrtf(ss), 1e-12f);
        v.x *= inv; v.y *= inv; v.z *= inv; v.w *= inv;
        o4[k * 64 + lane] = v;
    }
}

// ---------------- K4: partial online LSE over a q-chunk ----------------
// grid (NC, NCHUNK); block 256; partial (m,s) per (k,c,chunk)
__global__ void __launch_bounds__(256) k4_partial(const float* __restrict__ queues,
                                                  const float* __restrict__ keys,
                                                  float* __restrict__ mpart,
                                                  float* __restrict__ spart,
                                                  float* __restrict__ pos0) {
    int t = threadIdx.x;
    int c = blockIdx.x;
    int chunk = blockIdx.y;
    int lane = t & 63, wv = t >> 6;
    float key[K], m[K], s[K];
    #pragma unroll
    for (int k = 0; k < K; ++k) {
        key[k] = keys[k * NC + c] * INV_T;
        m[k] = -1e30f;
        s[k] = 0.f;
    }
    if (chunk == 0 && t < K)
        pos0[t * NC + c] = keys[t * NC + c] * INV_T * queues[(size_t)(t * NC + c) * Q];
    int qhi = min(Q, (chunk + 1) * QC);
    for (int q = chunk * QC + t; q < qhi; q += 256) {
        float qv[K];
        float qs = 0.f;
        #pragma unroll
        for (int k = 0; k < K; ++k) {
            qv[k] = queues[(size_t)(k * NC + c) * Q + q];
            qs += qv[k];
        }
        #pragma unroll
        for (int k = 0; k < K; ++k) {
            float a  = key[k] * qv[k];            // l_pos/T
            float bn = key[k] * (qs - qv[k]);     // l_neg/T
            float mx = fmaxf(a, bn);
            float mn = fmaxf(m[k], mx);
            s[k] = s[k] * __expf(m[k] - mn) + __expf(a - mn) + __expf(bn - mn);
            m[k] = mn;
        }
    }
    __shared__ float mw[K][4], sw[K][4];
    #pragma unroll
    for (int k = 0; k < K; ++k) {
        float mk = m[k], sk = s[k];
        #pragma unroll
        for (int off = 32; off > 0; off >>= 1) {
            float om = __shfl_xor(mk, off, 64);
            float os = __shfl_xor(sk, off, 64);
            float M  = fmaxf(mk, om);
            sk = sk * __expf(mk - M) + os * __expf(om - M);
            mk = M;
        }
        if (lane == 0) { mw[k][wv] = mk; sw[k][wv] = sk; }
    }
    __syncthreads();
    if (t < K) {
        float M = mw[t][0], S = sw[t][0];
        #pragma unroll
        for (int w2 = 1; w2 < 4; ++w2) {
            float M2 = fmaxf(M, mw[t][w2]);
            S = S * __expf(M - M2) + sw[t][w2] * __expf(mw[t][w2] - M2);
            M = M2;
        }
        mpart[((size_t)t * NC + c) * NCHUNK + chunk] = M;
        spart[((size_t)t * NC + c) * NCHUNK + chunk] = S;
    }
}

// ---------------- K5: merge chunks, compute loss ----------------
__global__ void k5_final(const float* __restrict__ mpart, const float* __restrict__ spart,
                         const float* __restrict__ pos0, const int* __restrict__ counts,
                         float* __restrict__ loss) {
    int t = threadIdx.x;   // = c
    float acc = 0.f;
    #pragma unroll
    for (int k = 0; k < K; ++k) {
        float4 mp = ((const float4*)mpart)[k * NC + t];
        float4 sp = ((const float4*)spart)[k * NC + t];
        float M = fmaxf(fmaxf(mp.x, mp.y), fmaxf(mp.z, mp.w));
        float S = sp.x * __expf(mp.x - M) + sp.y * __expf(mp.y - M)
                + sp.z * __expf(mp.z - M) + sp.w * __expf(mp.w - M);
        float lse = M + logf(S);
        if (counts[k] > 0) acc += lse - pos0[k * NC + t];
    }
    __shared__ float red[256];
    red[t] = acc;
    __syncthreads();
    for (int s = 128; s > 0; s >>= 1) {
        if (t < s) red[t] += red[t + s];
        __syncthreads();
    }
    if (t == 0) *loss = red[0] * (1.0f / 256.0f);
}

extern "C" void kernel_launch(void* const* d_in, const int* in_sizes, int n_in,
                              void* d_out, int out_size, void* d_ws, size_t ws_size,
                              hipStream_t stream) {
    const float* fea    = (const float*)d_in[0];   // [8,256,128,128]
    const float* res    = (const float*)d_in[1];   // [8,19,128,128]
    const float* queues = (const float*)d_in[2];   // [19,256,2975]

    float* out  = (float*)d_out;                   // res copy, then loss scalar
    float* loss = out + (size_t)BS * K * HW;       // element 2490368

    char* ws = (char*)d_ws;
    float*         sums   = (float*)(ws);                 // 19456 B
    float*         keys   = (float*)(ws + 19456);         // 19456 B
    int*           counts = (int*)(ws + 38912);           // 128 B (padded)
    unsigned char* pred   = (unsigned char*)(ws + 39040); // 131072 B
    float*         mpart  = (float*)(ws + 170112);        // K*NC*NCHUNK f32 = 77824 B
    float*         spart  = (float*)(ws + 247936);        // 77824 B
    float*         pos0   = (float*)(ws + 325760);        // 19456 B

    hipLaunchKernelGGL(k0_zero,    dim3(1),              dim3(256), 0, stream, sums, counts);
    hipLaunchKernelGGL(k1_argmax,  dim3(BS * HW / 512),  dim3(256), 0, stream, res, out, pred, counts);
    hipLaunchKernelGGL(k2_pool,    dim3(BS * NC),        dim3(256), 0, stream, fea, pred, sums);
    hipLaunchKernelGGL(k3_keys,    dim3(1),              dim3(256), 0, stream, sums, counts, keys);
    hipLaunchKernelGGL(k4_partial, dim3(NC, NCHUNK),     dim3(256), 0, stream, queues, keys, mpart, spart, pos0);
    hipLaunchKernelGGL(k5_final,   dim3(1),              dim3(256), 0, stream, mpart, spart, pos0, counts, loss);
}

// Round 3
// 72.703 us; speedup vs baseline: 1.1850x; 1.0592x over previous
//
#include <hip/hip_runtime.h>

#define HW 16384      // 128*128
#define BS 8
#define NC 256        // feature channels
#define K  19         // classes
#define Q  2975
#define INV_T 5.0f    // 1/0.2
#define NCHUNK 4
#define QC 744        // ceil(Q/NCHUNK)
#define NB1 256       // k1 grid size (per-block histograms)

// ---------------- K1: argmax + copy res->out + per-block histogram; block0 zeroes sums ----
// float2-vectorized: each thread owns 2 consecutive pixels; 256 blocks (1/CU)
__global__ void k1_argmax(const float* __restrict__ res, float* __restrict__ out,
                          unsigned char* __restrict__ pred, int* __restrict__ histb,
                          float* __restrict__ sums) {
    __shared__ int hist[K];
    int t = threadIdx.x;
    if (t < K) hist[t] = 0;
    __syncthreads();
    int gp2 = blockIdx.x * 256 + t;          // float2 group id
    int b   = gp2 >> 13;                     // / (HW/2)
    int p2  = gp2 & (HW / 2 - 1);
    const float2* rbase = (const float2*)(res + (size_t)b * K * HW) + p2;
    float2*       obase = (float2*)(out + (size_t)b * K * HW) + p2;
    float2 v = rbase[0];
    obase[0] = v;
    float bx = v.x, by = v.y;
    int   kx = 0,  ky = 0;
    #pragma unroll
    for (int k = 1; k < K; ++k) {
        float2 w = rbase[(size_t)k * (HW / 2)];
        obase[(size_t)k * (HW / 2)] = w;
        if (w.x > bx) { bx = w.x; kx = k; }
        if (w.y > by) { by = w.y; ky = k; }
    }
    uchar2* pp = (uchar2*)pred + ((size_t)b * (HW / 2) + p2);
    uchar2 pk; pk.x = (unsigned char)kx; pk.y = (unsigned char)ky;
    *pp = pk;
    atomicAdd(&hist[kx], 1);
    atomicAdd(&hist[ky], 1);
    if (blockIdx.x == 0) {                   // zero sums for k2 (runs after k1 completes)
        for (int i = t; i < K * NC; i += 256) sums[i] = 0.f;
    }
    __syncthreads();
    if (t < K) histb[t * NB1 + blockIdx.x] = hist[t];   // k-major, no global atomics
}

// ---------------- K2: per-class pooling: sums[k][c] = sum of fea over pred==k ----------------
// one block per (b,c) row; each thread owns LDS column acc[k][tid] -> no atomics,
// bank = tid%32 -> conflict-free
__global__ void __launch_bounds__(256) k2_pool(const float* __restrict__ fea,
                                               const unsigned char* __restrict__ pred,
                                               float* __restrict__ sums) {
    __shared__ float acc[K * 256];
    int t = threadIdx.x;
    int b = blockIdx.x >> 8;
    int c = blockIdx.x & 255;
    #pragma unroll
    for (int k = 0; k < K; ++k) acc[k * 256 + t] = 0.f;
    __syncthreads();
    const float4* f4 = (const float4*)(fea + (size_t)(b * NC + c) * HW);
    const uchar4* p4 = (const uchar4*)(pred + (size_t)b * HW);
    for (int i = t; i < HW / 4; i += 256) {
        float4 v  = f4[i];
        uchar4 kk = p4[i];
        acc[kk.x * 256 + t] += v.x;
        acc[kk.y * 256 + t] += v.y;
        acc[kk.z * 256 + t] += v.z;
        acc[kk.w * 256 + t] += v.w;
    }
    __syncthreads();
    for (int s = 128; s > 0; s >>= 1) {
        for (int idx = t; idx < K * s; idx += 256) {
            int k = idx / s, j = idx - k * s;
            acc[k * 256 + j] += acc[k * 256 + j + s];
        }
        __syncthreads();
    }
    if (t < K) atomicAdd(&sums[t * 256 + c], acc[t * 256]);
}

// ---------------- K4: fused keys-normalize + partial online LSE over a q-chunk -------------
// grid (NC, NCHUNK); block 256.
// keys = sums / max(||sums||, max(cnt,1)*1e-12)   (algebraically == reference)
__global__ void __launch_bounds__(256) k4_fused(const float* __restrict__ queues,
                                                const float* __restrict__ sums,
                                                const int* __restrict__ histb,
                                                float* __restrict__ mpart,
                                                float* __restrict__ spart,
                                                float* __restrict__ pos0,
                                                float* __restrict__ countsf) {
    int t = threadIdx.x;
    int c = blockIdx.x;
    int chunk = blockIdx.y;
    int lane = t & 63, wv = t >> 6;

    // --- phase A: per-class ||sums||^2 and counts (wave wv handles k = wv, wv+4, ...) ---
    __shared__ float nrm_sh[K], cnt_sh[K], key_sh[K];
    for (int k = wv; k < K; k += 4) {
        float ss = 0.f, cf = 0.f;
        #pragma unroll
        for (int j = 0; j < 4; ++j) {
            float v = sums[k * NC + j * 64 + lane];
            ss += v * v;
            cf += (float)histb[k * NB1 + j * 64 + lane];
        }
        #pragma unroll
        for (int off = 32; off > 0; off >>= 1) {
            ss += __shfl_xor(ss, off, 64);
            cf += __shfl_xor(cf, off, 64);
        }
        if (lane == 0) { nrm_sh[k] = ss; cnt_sh[k] = cf; }
    }
    __syncthreads();

    float key[K], m[K], s[K];
    #pragma unroll
    for (int k = 0; k < K; ++k) {
        float denom = fmaxf(sqrtf(nrm_sh[k]), fmaxf(cnt_sh[k], 1.0f) * 1e-12f);
        key[k] = sums[k * NC + c] / denom * INV_T;   // uniform addr -> broadcast load
        m[k] = -1e30f;
        s[k] = 0.f;
    }
    if (chunk == 0) {
        if (c == 0 && t < K) countsf[t] = cnt_sh[t];
        if (t == 0) {
            #pragma unroll
            for (int k = 0; k < K; ++k) key_sh[k] = key[k];
        }
        __syncthreads();
        if (t < K) pos0[t * NC + c] = key_sh[t] * queues[(size_t)(t * NC + c) * Q];
    }

    // --- phase B: online LSE over this chunk's q range ---
    int qhi = min(Q, (chunk + 1) * QC);
    for (int q = chunk * QC + t; q < qhi; q += 256) {
        float qv[K];
        float qs = 0.f;
        #pragma unroll
        for (int k = 0; k < K; ++k) {
            qv[k] = queues[(size_t)(k * NC + c) * Q + q];
            qs += qv[k];
        }
        #pragma unroll
        for (int k = 0; k < K; ++k) {
            float a  = key[k] * qv[k];                // l_pos/T
            float bn = fmaf(key[k], qs, -a);          // l_neg/T
            float mx = fmaxf(a, bn);
            if (mx > m[k]) { s[k] *= __expf(m[k] - mx); m[k] = mx; }  // rare after warmup
            s[k] += __expf(a - m[k]) + __expf(bn - m[k]);
        }
    }
    __shared__ float mw[K][4], sw[K][4];
    #pragma unroll
    for (int k = 0; k < K; ++k) {
        float mk = m[k], sk = s[k];
        #pragma unroll
        for (int off = 32; off > 0; off >>= 1) {
            float om = __shfl_xor(mk, off, 64);
            float os = __shfl_xor(sk, off, 64);
            float M  = fmaxf(mk, om);
            sk = sk * __expf(mk - M) + os * __expf(om - M);
            mk = M;
        }
        if (lane == 0) { mw[k][wv] = mk; sw[k][wv] = sk; }
    }
    __syncthreads();
    if (t < K) {
        float M = mw[t][0], S = sw[t][0];
        #pragma unroll
        for (int w2 = 1; w2 < 4; ++w2) {
            float M2 = fmaxf(M, mw[t][w2]);
            S = S * __expf(M - M2) + sw[t][w2] * __expf(mw[t][w2] - M2);
            M = M2;
        }
        mpart[((size_t)t * NC + c) * NCHUNK + chunk] = M;
        spart[((size_t)t * NC + c) * NCHUNK + chunk] = S;
    }
}

// ---------------- K5: merge chunks, compute loss ----------------
__global__ void k5_final(const float* __restrict__ mpart, const float* __restrict__ spart,
                         const float* __restrict__ pos0, const float* __restrict__ countsf,
                         float* __restrict__ loss) {
    int t = threadIdx.x;   // = c
    float acc = 0.f;
    #pragma unroll
    for (int k = 0; k < K; ++k) {
        float4 mp = ((const float4*)mpart)[k * NC + t];
        float4 sp = ((const float4*)spart)[k * NC + t];
        float M = fmaxf(fmaxf(mp.x, mp.y), fmaxf(mp.z, mp.w));
        float S = sp.x * __expf(mp.x - M) + sp.y * __expf(mp.y - M)
                + sp.z * __expf(mp.z - M) + sp.w * __expf(mp.w - M);
        float lse = M + logf(S);
        if (countsf[k] > 0.5f) acc += lse - pos0[k * NC + t];
    }
    __shared__ float red[256];
    red[t] = acc;
    __syncthreads();
    for (int s = 128; s > 0; s >>= 1) {
        if (t < s) red[t] += red[t + s];
        __syncthreads();
    }
    if (t == 0) *loss = red[0] * (1.0f / 256.0f);
}

extern "C" void kernel_launch(void* const* d_in, const int* in_sizes, int n_in,
                              void* d_out, int out_size, void* d_ws, size_t ws_size,
                              hipStream_t stream) {
    const float* fea    = (const float*)d_in[0];   // [8,256,128,128]
    const float* res    = (const float*)d_in[1];   // [8,19,128,128]
    const float* queues = (const float*)d_in[2];   // [19,256,2975]

    float* out  = (float*)d_out;                   // res copy, then loss scalar
    float* loss = out + (size_t)BS * K * HW;       // element 2490368

    char* ws = (char*)d_ws;
    float*         sums   = (float*)(ws);                 // 19456 B
    int*           histb  = (int*)(ws + 19456);           // K*NB1*4 = 19456 B
    float*         countsf= (float*)(ws + 38912);         // 128 B (padded)
    unsigned char* pred   = (unsigned char*)(ws + 39040); // 131072 B
    float*         mpart  = (float*)(ws + 170112);        // K*NC*NCHUNK f32 = 77824 B
    float*         spart  = (float*)(ws + 247936);        // 77824 B
    float*         pos0   = (float*)(ws + 325760);        // 19456 B

    hipLaunchKernelGGL(k1_argmax, dim3(NB1),         dim3(256), 0, stream, res, out, pred, histb, sums);
    hipLaunchKernelGGL(k2_pool,   dim3(BS * NC),     dim3(256), 0, stream, fea, pred, sums);
    hipLaunchKernelGGL(k4_fused,  dim3(NC, NCHUNK),  dim3(256), 0, stream, queues, sums, histb, mpart, spart, pos0, countsf);
    hipLaunchKernelGGL(k5_final,  dim3(1),           dim3(256), 0, stream, mpart, spart, pos0, countsf, loss);
}